// Round 3
// baseline (393.985 us; speedup 1.0000x reference)
//
#include <hip/hip_runtime.h>
#include <stdint.h>

// Problem constants (match reference)
#define NP 32    // num networks (P)
#define NH 128   // hidden (H)
#define NB 32    // batch (B)
#define NT 256   // time (T)
#define FH 512   // 4*H

typedef __attribute__((ext_vector_type(4))) float float4_t;
typedef __attribute__((ext_vector_type(8))) __bf16 bf16x8;
typedef __attribute__((ext_vector_type(4))) __bf16 bf16x4;

static __device__ __forceinline__ float4_t mfma_bf16(bf16x8 a, bf16x8 b, float4_t c) {
  return __builtin_amdgcn_mfma_f32_16x16x32_bf16(a, b, c, 0, 0, 0);
}

#define LOG2E 1.4426950408889634f

// Raw workgroup barrier: drains LDS ops only (cross-wave h visibility), does
// NOT drain vmcnt — pending global loads/stores stay in flight across it.
#define BAR() __asm__ volatile("s_waitcnt lgkmcnt(0)\n\ts_barrier" ::: "memory")

// Grid: 64 blocks = 32 networks x 2 batch-halves (16 batches each).
// Block: 512 threads = 8 waves; wave w owns hidden units [16w, 16w+16).
// Weights live in VGPRs as bf16 B-fragments, loaded once.
// Gate scales folded into weights/biases: i,f,o cols scaled by -log2e
// (sigmoid = rcp(1+exp2(y))), g cols by -2log2e (tanh = (1-e)*rcp(1+e)).
// X staged through LDS in bf16 A-frag layout, double-buffered 32-step tiles:
// the recurrence loop has NO global loads on its chain.
template<int STORE_HS>
__global__ __launch_bounds__(512, 2) void clstm_main(
    const float* __restrict__ X, const float* __restrict__ Wih,
    const float* __restrict__ Whh, const float* __restrict__ bih,
    const float* __restrict__ bhh, const float* __restrict__ Wout,
    const float* __restrict__ bout, float* __restrict__ out,
    __bf16* __restrict__ hs)
{
  const int net = blockIdx.x >> 1, bg = blockIdx.x & 1;
  const int tid = threadIdx.x;
  const int w = tid >> 6, lane = tid & 63;
  const int quad = lane >> 4, l16 = lane & 15;

  // h A-fragments, double buffered: [buf][kchunk][kquad][m][j] (16B rows)
  __shared__ __bf16 hfrag[2][4][4][16][8];
  // x A-fragments: [buf][t mod 32][kquad][m(batch)][j] — 1KB per t-row
  __shared__ __bf16 xtile[2][32][4][16][8];
  // per-wave output partials (fallback path only)
  __shared__ float opart[2][8][16];

  { // zero the t=0 h buffer (h0 = 0): 4KB = 1024 ints, 2 per thread
    int* hz = (int*)&hfrag[0][0][0][0][0];
    hz[2*tid] = 0; hz[2*tid+1] = 0;
  }

  // ---- prefill xtile buf 0 with t = 0..31 (one-time) ----
  // round r: tt = r*4 + tid>>7; thread covers (b16, d4): float4 of X.
  {
    const int sub = tid & 127, b16p = sub >> 3, d4 = sub & 7;
    const float* xb = X + (size_t)(bg*16 + b16p)*(NT*NP) + d4*4;
#pragma unroll
    for (int r = 0; r < 8; ++r) {
      const int tt = r*4 + (tid >> 7);
      float4_t v = *(const float4_t*)(xb + tt*NP);
      bf16x4 bv;
      bv[0] = (__bf16)v[0]; bv[1] = (__bf16)v[1];
      bv[2] = (__bf16)v[2]; bv[3] = (__bf16)v[3];
      *(bf16x4*)&xtile[0][tt][d4 >> 1][b16p][(d4 & 1)*4] = bv;
    }
  }
  __syncthreads();  // once, outside the loop

  // ---- load weights into register B-fragments (one-time) ----
  bf16x8 bfrag[4][5];
  float bias[4];
#pragma unroll
  for (int g = 0; g < 4; ++g) {
    const float scale = (g == 2) ? (-2.0f*LOG2E) : (-LOG2E);
    const int col = g*NH + w*16 + l16;
#pragma unroll
    for (int kc = 0; kc < 5; ++kc) {
      const float* src = (kc == 0) ? (Wih + (net*FH + col)*NP + quad*8)
                                   : (Whh + (net*FH + col)*NH + (kc-1)*32 + quad*8);
      bf16x8 bf;
#pragma unroll
      for (int j = 0; j < 8; ++j) bf[j] = (__bf16)(src[j] * scale);
      bfrag[g][kc] = bf;
    }
    bias[g] = (bih[net*FH + col] + bhh[net*FH + col]) * scale;
  }
  const float woj = Wout[net*NH + w*16 + l16];  // fallback head weight
  const float bo  = bout[net];

  float4_t c4 = {0.f, 0.f, 0.f, 0.f};  // c state: lane's unit, batches quad*4+r

  // where this lane's h values land in the next-step A-frag layout
  const int hj = w*16 + l16;                       // hidden unit index 0..127
  const int kcp = hj >> 5, q2 = (hj >> 3) & 3, jj = hj & 7;

  // hs store base: hs[((t*NP + net)*NB + b)*NH + hj], b = bg*16 + quad*4 + r
  __bf16* hsp = STORE_HS ? (hs + ((size_t)net*NB + bg*16 + quad*4)*NH + hj) : nullptr;

  // in-loop x staging: thread covers (b16s, ds); loads t+32, writes buf^1
  const int b16s = tid >> 5, ds = tid & 31;
  const float* xsrc = X + (size_t)(bg*16 + b16s)*(NT*NP) + ds;

  for (int t = 0; t < NT; ++t) {
    const int rd = t & 1, wr = rd ^ 1;
    const int xbuf = (t >> 5) & 1;

    // ---- 1. LDS reads first (latency ~120 cyc): h frags + x frag ----
    bf16x8 ah[4];
#pragma unroll
    for (int kc = 0; kc < 4; ++kc)
      ah[kc] = *(const bf16x8*)&hfrag[rd][kc][quad][l16][0];
    bf16x8 ax = *(const bf16x8*)&xtile[xbuf][t & 31][quad][l16][0];

    // ---- 2. issue x staging load for t+32 (fire-and-forget) ----
    float xstage = 0.f;
    const bool do_stage = (t + 32) < NT;
    if (do_stage) xstage = xsrc[(t + 32)*NP];

    // ---- 3. MFMA: two parallel chains per gate (depth 3+2, then add) ----
    float4_t acc[4];
#pragma unroll
    for (int g = 0; g < 4; ++g) {
      float4_t a0 = {bias[g], bias[g], bias[g], bias[g]};
      float4_t a1 = {0.f, 0.f, 0.f, 0.f};
      a0 = mfma_bf16(ax,    bfrag[g][0], a0);
      a1 = mfma_bf16(ah[2], bfrag[g][3], a1);
      a0 = mfma_bf16(ah[0], bfrag[g][1], a0);
      a1 = mfma_bf16(ah[3], bfrag[g][4], a1);
      a0 = mfma_bf16(ah[1], bfrag[g][2], a0);
      acc[g] = a0 + a1;
    }

    // ---- 4. activations + state update (fp32) ----
    float4_t h4, po;
#pragma unroll
    for (int r = 0; r < 4; ++r) {
      float ei = __builtin_amdgcn_exp2f(acc[0][r]);           // exp(-i_pre)
      float ig = __builtin_amdgcn_rcpf(1.0f + ei);            // sigmoid
      float ef = __builtin_amdgcn_exp2f(acc[1][r]);
      float fg = __builtin_amdgcn_rcpf(1.0f + ef);
      float eg = __builtin_amdgcn_exp2f(fminf(acc[2][r], 126.0f)); // exp(-2 g_pre)
      float rg = __builtin_amdgcn_rcpf(1.0f + eg);
      float gg = (1.0f - eg) * rg;                            // tanh
      float eo = __builtin_amdgcn_exp2f(acc[3][r]);
      float og = __builtin_amdgcn_rcpf(1.0f + eo);
      float c  = fg * c4[r] + ig * gg;
      c4[r] = c;
      float ec = __builtin_amdgcn_exp2f(fminf(c * (-2.0f*LOG2E), 126.0f));
      float rc = __builtin_amdgcn_rcpf(1.0f + ec);
      float th = (1.0f - ec) * rc;                            // tanh(c)
      float h  = og * th;
      h4[r] = h;
      if (!STORE_HS) po[r] = h * woj;
    }

    // ---- 5. write h' (bf16) to next-step A-frag buffer + hs (fire&forget) ----
#pragma unroll
    for (int r = 0; r < 4; ++r) {
      __bf16 hb = (__bf16)h4[r];
      hfrag[wr][kcp][q2][quad*4 + r][jj] = hb;
      if (STORE_HS) hsp[((size_t)t*NP*NB + r)*NH] = hb;
    }

    // ---- 6. complete x staging (off the h-chain; consumed 32 steps later) ----
    if (do_stage)
      xtile[xbuf ^ 1][t & 31][ds >> 3][b16s][ds & 7] = (__bf16)xstage;

    if (!STORE_HS) {
#pragma unroll
      for (int m = 1; m < 16; m <<= 1) {
#pragma unroll
        for (int r = 0; r < 4; ++r) po[r] += __shfl_xor(po[r], m, 64);
      }
      if (l16 == 0) *(float4_t*)&opart[rd][w][quad*4] = po;
    }

    BAR();  // lgkmcnt-only barrier

    if (!STORE_HS) {
      if (lane < 16) {
        const int w8 = lane & 7, bl = 2*w + (lane >> 3);
        float v = opart[rd][w8][bl];
        v += __shfl_xor(v, 1, 64);
        v += __shfl_xor(v, 2, 64);
        v += __shfl_xor(v, 4, 64);
        if (w8 == 0) out[(size_t)(bg*16 + bl)*(NT*NP) + t*NP + net] = v + bo;
      }
    }
  }
}

// Head v2: out[b][t][n] = sum_h hs[t][n][b][h]*Wout[n][h] + bout[n].
// One block per t (8 waves); wave w round r handles net = w*4+r.
// Loads are lane-contiguous within an 8KB (net,t) slab — no HBM read amp.
// Store via LDS transpose: 128B contiguous per batch row.
__global__ __launch_bounds__(512, 2) void clstm_head(
    const __bf16* __restrict__ hs, const float* __restrict__ Wout,
    const float* __restrict__ bout, float* __restrict__ out)
{
  const int t = blockIdx.x;
  const int tid = threadIdx.x;
  const int w = tid >> 6, lane = tid & 63;
  __shared__ float sums[NP][NB];

  const int b = lane >> 1, half = lane & 1;
#pragma unroll
  for (int r = 0; r < 4; ++r) {
    const int net = w*4 + r;
    const __bf16* hp = hs + (((size_t)t*NP + net)*NB + b)*NH + half*64;
    const float* wp = Wout + net*NH + half*64;
    float acc = 0.f;
#pragma unroll
    for (int c = 0; c < 8; ++c) {
      bf16x8 hv = *(const bf16x8*)(hp + c*8);
      float4_t w0 = *(const float4_t*)(wp + c*8);
      float4_t w1 = *(const float4_t*)(wp + c*8 + 4);
      acc += (float)hv[0]*w0[0] + (float)hv[1]*w0[1] +
             (float)hv[2]*w0[2] + (float)hv[3]*w0[3] +
             (float)hv[4]*w1[0] + (float)hv[5]*w1[1] +
             (float)hv[6]*w1[2] + (float)hv[7]*w1[3];
    }
    acc += __shfl_xor(acc, 1, 64);
    if (half == 0) sums[net][b] = acc;
  }
  __syncthreads();

  if (tid < 256) {
    const int bb = tid >> 3, nq = tid & 7;
    float4_t v;
#pragma unroll
    for (int k = 0; k < 4; ++k) v[k] = sums[nq*4 + k][bb] + bout[nq*4 + k];
    *(float4_t*)(out + (size_t)bb*(NT*NP) + t*NP + nq*4) = v;
  }
}

extern "C" void kernel_launch(void* const* d_in, const int* in_sizes, int n_in,
                              void* d_out, int out_size, void* d_ws, size_t ws_size,
                              hipStream_t stream) {
  const float* X    = (const float*)d_in[0];
  const float* Wih  = (const float*)d_in[1];
  const float* Whh  = (const float*)d_in[2];
  const float* bih  = (const float*)d_in[3];
  const float* bhh  = (const float*)d_in[4];
  const float* Wout = (const float*)d_in[5];
  const float* bout = (const float*)d_in[6];
  float* out = (float*)d_out;
  (void)in_sizes; (void)n_in; (void)out_size;

  const size_t hs_bytes = (size_t)NT * NP * NB * NH * sizeof(__bf16); // 64 MB
  if (ws_size >= hs_bytes) {
    __bf16* hsb = (__bf16*)d_ws;
    clstm_main<1><<<64, 512, 0, stream>>>(X, Wih, Whh, bih, bhh, Wout, bout, out, hsb);
    clstm_head<<<NT, 512, 0, stream>>>(hsb, Wout, bout, out);
  } else {
    clstm_main<0><<<64, 512, 0, stream>>>(X, Wih, Whh, bih, bhh, Wout, bout, out, nullptr);
  }
}

// Round 4
// 387.176 us; speedup vs baseline: 1.0176x; 1.0176x over previous
//
#include <hip/hip_runtime.h>
#include <stdint.h>

// Problem constants (match reference)
#define NP 32    // num networks (P)
#define NH 128   // hidden (H)
#define NB 32    // batch (B)
#define NT 256   // time (T)
#define FH 512   // 4*H

typedef __attribute__((ext_vector_type(4))) float float4_t;
typedef __attribute__((ext_vector_type(8))) __bf16 bf16x8;

static __device__ __forceinline__ float4_t mfma_bf16(bf16x8 a, bf16x8 b, float4_t c) {
  return __builtin_amdgcn_mfma_f32_16x16x32_bf16(a, b, c, 0, 0, 0);
}

#define LOG2E 1.4426950408889634f

// Raw workgroup barrier: drains LDS ops only (cross-wave h visibility), does
// NOT drain vmcnt — pending global loads/stores stay in flight across it.
#define BAR() __asm__ volatile("s_waitcnt lgkmcnt(0)\n\ts_barrier" ::: "memory")

// Grid: 64 blocks = 32 networks x 2 batch-halves (16 batches each).
// Block: 256 threads = 4 FAT waves; wave w owns units [32w, 32w+32) =
// 2 unit-tiles x 4 gates = 8 MFMA N-tiles. Rationale vs 8x16-unit waves:
// every wave reads the SAME 4KB h A-fragment per step; LDS read traffic is
// waves x 4KB, so 4 waves halve LDS serialization (~190 cyc/step vs ~380)
// and halve barrier participants. Per-SIMD MFMA/trans/VALU issue invariant.
// Weights in VGPRs: bfrag[2][4][5] = 160 VGPRs/lane -> launch_bounds(256,1).
// Gate scales folded into weights/biases: i,f,o cols scaled by -log2e
// (sigmoid = rcp(1+exp2(y))), g cols by -2log2e (tanh = (1-e)*rcp(1+e)).
// x comes via register prefetch (R2 scheme) — NO global/LDS op on the
// lgkm-drained chain (R3's xtile regression post-mortem).
template<int STORE_HS>
__global__ __launch_bounds__(256, 1) void clstm_main(
    const float* __restrict__ X, const float* __restrict__ Wih,
    const float* __restrict__ Whh, const float* __restrict__ bih,
    const float* __restrict__ bhh, const float* __restrict__ Wout,
    const float* __restrict__ bout, float* __restrict__ out,
    __bf16* __restrict__ hs)
{
  const int net = blockIdx.x >> 1, bg = blockIdx.x & 1;
  const int tid = threadIdx.x;
  const int w = tid >> 6, lane = tid & 63;
  const int quad = lane >> 4, l16 = lane & 15;

  // h A-fragments, double buffered: [buf][kchunk][kquad][m][j] (16B rows)
  __shared__ __bf16 hfrag[2][4][4][16][8];
  // per-wave output partials (fallback path only): [buf][wave][batch]
  __shared__ float opart[2][4][16];

  { // zero the t=0 h buffer (h0 = 0): 4KB; 256 threads x 16B
    int* hz = (int*)&hfrag[0][0][0][0][0];
    hz[4*tid] = 0; hz[4*tid+1] = 0; hz[4*tid+2] = 0; hz[4*tid+3] = 0;
  }
  __syncthreads();  // once, outside the loop — full drain fine here

  // ---- load weights into register B-fragments (one-time) ----
  // B-frag layout for 16x16x32: lane holds B[k = quad*8 + j][n = l16].
  // ut in {0,1}: unit u = 32w + 16*ut + l16; gate col = g*128 + u.
  bf16x8 bfrag[2][4][5];
  float bias[2][4];
#pragma unroll
  for (int ut = 0; ut < 2; ++ut) {
#pragma unroll
    for (int g = 0; g < 4; ++g) {
      const float scale = (g == 2) ? (-2.0f*LOG2E) : (-LOG2E);
      const int col = g*NH + 32*w + 16*ut + l16;
#pragma unroll
      for (int kc = 0; kc < 5; ++kc) {
        const float* src = (kc == 0) ? (Wih + ((size_t)net*FH + col)*NP + quad*8)
                                     : (Whh + ((size_t)net*FH + col)*NH + (kc-1)*32 + quad*8);
        bf16x8 bf;
#pragma unroll
        for (int j = 0; j < 8; ++j) bf[j] = (__bf16)(src[j] * scale);
        bfrag[ut][g][kc] = bf;
      }
      bias[ut][g] = (bih[net*FH + col] + bhh[net*FH + col]) * scale;
    }
  }
  const float woj0 = Wout[net*NH + 32*w + l16];        // fallback head weights
  const float woj1 = Wout[net*NH + 32*w + 16 + l16];
  const float bo   = bout[net];

  float4_t c4[2] = {{0.f,0.f,0.f,0.f},{0.f,0.f,0.f,0.f}};  // c state

  // x A-frag source: lane reads X[bg*16+l16][t][quad*8 .. +8]
  const float* xrow = X + (size_t)(bg*16 + l16)*(NT*NP) + quad*8;

  // h write coords: unit j = 32w + 16*ut + l16 -> kchunk = w,
  // q2 = (16*ut + l16)>>3 = 2*ut + (l16>>3), jj = l16 & 7.
  const int q2lo = l16 >> 3, jj = l16 & 7;

  // hs store base: hs[((t*NP+net)*NB + b)*NH + u], b = bg*16 + quad*4 + r
  __bf16* hq = STORE_HS
      ? (hs + ((size_t)net*NB + bg*16 + quad*4)*NH + 32*w + l16) : nullptr;

  // preload + convert x for t=0
  bf16x8 ax;
  {
    float xv0[8];
    *(float4_t*)&xv0[0] = *(const float4_t*)xrow;
    *(float4_t*)&xv0[4] = *(const float4_t*)(xrow + 4);
#pragma unroll
    for (int j = 0; j < 8; ++j) ax[j] = (__bf16)xv0[j];
  }

  for (int t = 0; t < NT; ++t) {
    const int rd = t & 1, wr = rd ^ 1;

    // ---- 1. h A-frags first (latency ~120 cyc; identical across waves) ----
    bf16x8 ah[4];
#pragma unroll
    for (int kc = 0; kc < 4; ++kc)
      ah[kc] = *(const bf16x8*)&hfrag[rd][kc][quad][l16][0];

    // ---- 2. prefetch x for t+1 (fire-and-forget; converted at step end) ----
    float xv[8];
    {
      const int tn = (t + 1 < NT) ? t + 1 : t;
      const float* xp = xrow + tn*NP;
      *(float4_t*)&xv[0] = *(const float4_t*)xp;
      *(float4_t*)&xv[4] = *(const float4_t*)(xp + 4);
    }

    // ---- 3. MFMA: 8 N-tiles, two parallel chains each (depth 3+2) ----
    float4_t acc[2][4];
#pragma unroll
    for (int ut = 0; ut < 2; ++ut) {
#pragma unroll
      for (int g = 0; g < 4; ++g) {
        float4_t a0 = {bias[ut][g], bias[ut][g], bias[ut][g], bias[ut][g]};
        float4_t a1 = {0.f, 0.f, 0.f, 0.f};
        a0 = mfma_bf16(ax,    bfrag[ut][g][0], a0);
        a1 = mfma_bf16(ah[2], bfrag[ut][g][3], a1);
        a0 = mfma_bf16(ah[0], bfrag[ut][g][1], a0);
        a1 = mfma_bf16(ah[3], bfrag[ut][g][4], a1);
        a0 = mfma_bf16(ah[1], bfrag[ut][g][2], a0);
        acc[ut][g] = a0 + a1;
      }
    }

    // ---- 4. activations + state update (fp32), 8 updates/lane ----
    float4_t h4[2], po;
#pragma unroll
    for (int ut = 0; ut < 2; ++ut) {
#pragma unroll
      for (int r = 0; r < 4; ++r) {
        float ei = __builtin_amdgcn_exp2f(acc[ut][0][r]);
        float ig = __builtin_amdgcn_rcpf(1.0f + ei);            // sigmoid(i)
        float ef = __builtin_amdgcn_exp2f(acc[ut][1][r]);
        float fg = __builtin_amdgcn_rcpf(1.0f + ef);            // sigmoid(f)
        float eg = __builtin_amdgcn_exp2f(fminf(acc[ut][2][r], 126.0f));
        float rg = __builtin_amdgcn_rcpf(1.0f + eg);
        float gg = (1.0f - eg) * rg;                            // tanh(g)
        float eo = __builtin_amdgcn_exp2f(acc[ut][3][r]);
        float og = __builtin_amdgcn_rcpf(1.0f + eo);            // sigmoid(o)
        float c  = fg * c4[ut][r] + ig * gg;
        c4[ut][r] = c;
        float ec = __builtin_amdgcn_exp2f(fminf(c * (-2.0f*LOG2E), 126.0f));
        float rc = __builtin_amdgcn_rcpf(1.0f + ec);
        float th = (1.0f - ec) * rc;                            // tanh(c)
        h4[ut][r] = og * th;
      }
    }
    if (!STORE_HS) {
#pragma unroll
      for (int r = 0; r < 4; ++r) po[r] = h4[0][r]*woj0 + h4[1][r]*woj1;
    }

    // ---- 5. write h' (bf16) to next-step A-frag buffer + hs (fire&forget) ----
#pragma unroll
    for (int ut = 0; ut < 2; ++ut) {
#pragma unroll
      for (int r = 0; r < 4; ++r) {
        __bf16 hb = (__bf16)h4[ut][r];
        hfrag[wr][w][2*ut + q2lo][quad*4 + r][jj] = hb;
        if (STORE_HS) hq[(size_t)t*(NP*NB*NH) + r*NH + ut*16] = hb;
      }
    }

    // ---- 6. convert next x (off the lgkm chain) ----
#pragma unroll
    for (int j = 0; j < 8; ++j) ax[j] = (__bf16)xv[j];

    if (!STORE_HS) {
      // wave-level reduce over 16 unit-lanes
#pragma unroll
      for (int m = 1; m < 16; m <<= 1) {
#pragma unroll
        for (int r = 0; r < 4; ++r) po[r] += __shfl_xor(po[r], m, 64);
      }
      if (l16 == 0) *(float4_t*)&opart[rd][w][quad*4] = po;
    }

    BAR();  // lgkmcnt-only barrier

    if (!STORE_HS) {
      if (w == 0 && lane < 16) {
        float v = opart[rd][0][lane] + opart[rd][1][lane]
                + opart[rd][2][lane] + opart[rd][3][lane];
        out[(size_t)(bg*16 + lane)*(NT*NP) + t*NP + net] = v + bo;
      }
    }
  }
}

// Head v3: out[b][t][n] = sum_h hs[t][n][b][h]*Wout[n][h] + bout[n].
// One OUTPUT per lane; each lane reads a CONTIGUOUS 256B hs row (16 x bf16x8,
// all independent -> 16 loads in flight). 4096 waves total (1024 blocks x 4),
// wave gw: t = gw>>4, nets 2*(gw&15)+{0,1} split across half-waves.
__global__ __launch_bounds__(256, 4) void clstm_head(
    const __bf16* __restrict__ hs, const float* __restrict__ Wout,
    const float* __restrict__ bout, float* __restrict__ out)
{
  const int gw = blockIdx.x * 4 + (threadIdx.x >> 6);
  const int lane = threadIdx.x & 63;
  const int t = gw >> 4, sub = gw & 15;
  const int net = 2*sub + (lane >> 5), b = lane & 31;
  const __bf16* hp = hs + (((size_t)t*NP + net)*NB + b)*NH;
  const float* wp = Wout + net*NH;
  float acc = 0.f;
#pragma unroll
  for (int c = 0; c < 16; ++c) {
    bf16x8 hv = *(const bf16x8*)(hp + c*8);
    float4_t w0 = *(const float4_t*)(wp + c*8);
    float4_t w1 = *(const float4_t*)(wp + c*8 + 4);
    acc += (float)hv[0]*w0[0] + (float)hv[1]*w0[1] +
           (float)hv[2]*w0[2] + (float)hv[3]*w0[3] +
           (float)hv[4]*w1[0] + (float)hv[5]*w1[1] +
           (float)hv[6]*w1[2] + (float)hv[7]*w1[3];
  }
  out[((size_t)b*NT + t)*NP + net] = acc + bout[net];
}

extern "C" void kernel_launch(void* const* d_in, const int* in_sizes, int n_in,
                              void* d_out, int out_size, void* d_ws, size_t ws_size,
                              hipStream_t stream) {
  const float* X    = (const float*)d_in[0];
  const float* Wih  = (const float*)d_in[1];
  const float* Whh  = (const float*)d_in[2];
  const float* bih  = (const float*)d_in[3];
  const float* bhh  = (const float*)d_in[4];
  const float* Wout = (const float*)d_in[5];
  const float* bout = (const float*)d_in[6];
  float* out = (float*)d_out;
  (void)in_sizes; (void)n_in; (void)out_size;

  const size_t hs_bytes = (size_t)NT * NP * NB * NH * sizeof(__bf16); // 64 MB
  if (ws_size >= hs_bytes) {
    __bf16* hsb = (__bf16*)d_ws;
    clstm_main<1><<<64, 256, 0, stream>>>(X, Wih, Whh, bih, bhh, Wout, bout, out, hsb);
    clstm_head<<<1024, 256, 0, stream>>>(hsb, Wout, bout, out);
  } else {
    clstm_main<0><<<64, 256, 0, stream>>>(X, Wih, Whh, bih, bhh, Wout, bout, out, nullptr);
  }
}

// Round 5
// 336.137 us; speedup vs baseline: 1.1721x; 1.1518x over previous
//
#include <hip/hip_runtime.h>
#include <stdint.h>

// Problem constants (match reference)
#define NP 32    // num networks (P)
#define NH 128   // hidden (H)
#define NB 32    // batch (B)
#define NT 256   // time (T)
#define FH 512   // 4*H

typedef __attribute__((ext_vector_type(4))) float float4_t;
typedef __attribute__((ext_vector_type(8))) __bf16 bf16x8;

static __device__ __forceinline__ float4_t mfma_bf16(bf16x8 a, bf16x8 b, float4_t c) {
  return __builtin_amdgcn_mfma_f32_16x16x32_bf16(a, b, c, 0, 0, 0);
}

#define LOG2E 1.4426950408889634f

// Raw workgroup barrier: drains LDS ops only (cross-wave h visibility), does
// NOT drain vmcnt — pending global loads/stores stay in flight across it.
#define BAR() __asm__ volatile("s_waitcnt lgkmcnt(0)\n\ts_barrier" ::: "memory")

// R5 design. Evidence (R2/R4 counters, 256-CU normalization): the recurrence
// is ISSUE-bound on active CUs (local VALU ~62% + MFMA ~28%), dominated by
// ~10 transcendentals per (batch,unit) pair at 1/4 rate. Per-CU trans issue
// = pairs_per_block*10/32 cyc; the only way down is more blocks.
//
// Grid: 128 blocks = 32 nets x 4 batch-quarters (8 batches each; MFMA M=16
// tile half-filled: A rows 8..15 zero/dup, C rows 8..15 garbage, contained).
// Block: 512 thr = 8 waves (2 waves/SIMD — R4 showed 1 wave/SIMD exposes all
// latency); wave w owns units [16w,16w+16) = 4 gate N-tiles.
// Redistribution: valid C rows 0..7 live in quads 0,1 (4 regs each). One
// shfl_xor(32) moves regs 2,3 to quads 2,3 -> every lane owns exactly 2
// real (row,unit) pairs -> trans+pointwise issue per CU HALVES vs R2.
//   lane's rows: row0 = ((quad&1)<<2)|((quad>>1)<<1), row1 = row0+1.
// Head fused (no hs buffer, no 2nd kernel — the ~76us head kernel is gone):
//   po (pair h * Wout) reduced over l16 one step LATE (post-barrier, overlaps
//   next step's LDS latency), written to opart[(t-1)&1]; finalized (8-wave
//   sum + bias + out store) two steps late from opart[t&1]; epilogue drains.
__global__ __launch_bounds__(512, 2) void clstm_fused(
    const float* __restrict__ X, const float* __restrict__ Wih,
    const float* __restrict__ Whh, const float* __restrict__ bih,
    const float* __restrict__ bhh, const float* __restrict__ Wout,
    const float* __restrict__ bout, float* __restrict__ out)
{
  const int net = blockIdx.x >> 2, bq = blockIdx.x & 3;
  const int tid = threadIdx.x;
  const int w = tid >> 6, lane = tid & 63;
  const int quad = lane >> 4, l16 = lane & 15;

  // h A-fragments, double buffered: [buf][kchunk][kquad][m][j]; rows 8..15
  // stay zero forever (zeroed here, writes only touch rows 0..7).
  __shared__ __bf16 hfrag[2][4][4][16][8];          // 8 KB
  // head partials: [buf][local_batch_row][wave]
  __shared__ float opart[2][8][8];                  // 512 B

  { // zero BOTH hfrag buffers: 8KB = 2048 ints, 4 per thread
    int* hz = (int*)hfrag;
    hz[4*tid] = 0; hz[4*tid+1] = 0; hz[4*tid+2] = 0; hz[4*tid+3] = 0;
  }
  __syncthreads();  // once, outside the loop

  // ---- load weights into register B-fragments (one-time) ----
  // B-frag layout for 16x16x32: lane holds B[k = quad*8 + j][n = l16].
  bf16x8 bfrag[4][5];
  float bias[4];
#pragma unroll
  for (int g = 0; g < 4; ++g) {
    const float scale = (g == 2) ? (-2.0f*LOG2E) : (-LOG2E);
    const int col = g*NH + w*16 + l16;
#pragma unroll
    for (int kc = 0; kc < 5; ++kc) {
      const float* src = (kc == 0) ? (Wih + ((size_t)net*FH + col)*NP + quad*8)
                                   : (Whh + ((size_t)net*FH + col)*NH + (kc-1)*32 + quad*8);
      bf16x8 bf;
#pragma unroll
      for (int j = 0; j < 8; ++j) bf[j] = (__bf16)(src[j] * scale);
      bfrag[g][kc] = bf;
    }
    bias[g] = (bih[net*FH + col] + bhh[net*FH + col]) * scale;
  }
  const float woj = Wout[net*NH + w*16 + l16];  // this lane's unit head weight
  const float bo  = bout[net];

  float c0 = 0.f, c1 = 0.f;        // c state for the lane's 2 pairs
  float po_p0 = 0.f, po_p1 = 0.f;  // previous step's head partials

  // x A-frag source: row m = l16 -> batch bq*8 + (l16&7) (rows 8..15 dup, harmless)
  const float* xrow = X + (size_t)(bq*8 + (l16 & 7))*(NT*NP) + quad*8;

  // h write coords for unit u = w*16 + l16
  const int kcp = w >> 1, q2 = ((w & 1) << 1) | (l16 >> 3), jj = l16 & 7;
  // this lane's two local batch rows after redistribution
  const int row0 = ((quad & 1) << 2) | ((quad >> 1) << 1);

  // preload + convert x for t=0
  bf16x8 ax;
  {
    float xv0[8];
    *(float4_t*)&xv0[0] = *(const float4_t*)xrow;
    *(float4_t*)&xv0[4] = *(const float4_t*)(xrow + 4);
#pragma unroll
    for (int j = 0; j < 8; ++j) ax[j] = (__bf16)xv0[j];
  }

  for (int t = 0; t < NT; ++t) {
    const int rd = t & 1, wr = rd ^ 1;

    // ---- 1. h A-frags first (LDS latency overlapped by 2-4 below) ----
    bf16x8 ah[4];
#pragma unroll
    for (int kc = 0; kc < 4; ++kc)
      ah[kc] = *(const bf16x8*)&hfrag[rd][kc][quad][l16][0];

    // ---- 2. finalize out for data step t-2 (wave 7, lanes 0..7) ----
    if (w == 7 && lane < 8 && t >= 2) {
      float4_t p0 = *(const float4_t*)&opart[t & 1][lane][0];
      float4_t p1 = *(const float4_t*)&opart[t & 1][lane][4];
      float v = p0[0]+p0[1]+p0[2]+p0[3]+p1[0]+p1[1]+p1[2]+p1[3] + bo;
      out[((size_t)(bq*8 + lane)*NT + (t - 2))*NP + net] = v;
    }

    // ---- 3. reduce previous step's head partials (post-barrier = off-chain)
    {
      float a0 = po_p0, a1 = po_p1;
#pragma unroll
      for (int m = 1; m < 16; m <<= 1) {
        a0 += __shfl_xor(a0, m, 64);
        a1 += __shfl_xor(a1, m, 64);
      }
      if (l16 == 0) {
        opart[(t - 1) & 1][row0    ][w] = a0;
        opart[(t - 1) & 1][row0 + 1][w] = a1;
      }
    }

    // ---- 4. prefetch x for t+1 ----
    float xv[8];
    {
      const int tn = (t + 1 < NT) ? t + 1 : t;
      const float* xp = xrow + tn*NP;
      *(float4_t*)&xv[0] = *(const float4_t*)xp;
      *(float4_t*)&xv[4] = *(const float4_t*)(xp + 4);
    }

    // ---- 5. MFMA: 4 gates, two parallel chains each (depth 3+2) ----
    float4_t acc[4];
#pragma unroll
    for (int g = 0; g < 4; ++g) {
      float4_t a0 = {bias[g], bias[g], bias[g], bias[g]};
      float4_t a1 = {0.f, 0.f, 0.f, 0.f};
      a0 = mfma_bf16(ax,    bfrag[g][0], a0);
      a1 = mfma_bf16(ah[2], bfrag[g][3], a1);
      a0 = mfma_bf16(ah[0], bfrag[g][1], a0);
      a1 = mfma_bf16(ah[3], bfrag[g][4], a1);
      a0 = mfma_bf16(ah[1], bfrag[g][2], a0);
      acc[g] = a0 + a1;
    }

    // ---- 6. redistribute: quads 2,3 adopt regs 2,3 of quads 0,1 ----
    float g2[4][2];
#pragma unroll
    for (int g = 0; g < 4; ++g) {
      float s0 = __shfl_xor(acc[g][2], 32, 64);
      float s1 = __shfl_xor(acc[g][3], 32, 64);
      g2[g][0] = (quad < 2) ? acc[g][0] : s0;
      g2[g][1] = (quad < 2) ? acc[g][1] : s1;
    }

    // ---- 7. activations + state update: exactly 2 real pairs per lane ----
    float h0, h1;
    {
      float ei = __builtin_amdgcn_exp2f(g2[0][0]);
      float ig = __builtin_amdgcn_rcpf(1.0f + ei);
      float ef = __builtin_amdgcn_exp2f(g2[1][0]);
      float fg = __builtin_amdgcn_rcpf(1.0f + ef);
      float eg = __builtin_amdgcn_exp2f(fminf(g2[2][0], 126.0f));
      float rg = __builtin_amdgcn_rcpf(1.0f + eg);
      float gg = (1.0f - eg) * rg;
      float eo = __builtin_amdgcn_exp2f(g2[3][0]);
      float og = __builtin_amdgcn_rcpf(1.0f + eo);
      c0 = fg * c0 + ig * gg;
      float ec = __builtin_amdgcn_exp2f(fminf(c0 * (-2.0f*LOG2E), 126.0f));
      float rc = __builtin_amdgcn_rcpf(1.0f + ec);
      h0 = og * ((1.0f - ec) * rc);
    }
    {
      float ei = __builtin_amdgcn_exp2f(g2[0][1]);
      float ig = __builtin_amdgcn_rcpf(1.0f + ei);
      float ef = __builtin_amdgcn_exp2f(g2[1][1]);
      float fg = __builtin_amdgcn_rcpf(1.0f + ef);
      float eg = __builtin_amdgcn_exp2f(fminf(g2[2][1], 126.0f));
      float rg = __builtin_amdgcn_rcpf(1.0f + eg);
      float gg = (1.0f - eg) * rg;
      float eo = __builtin_amdgcn_exp2f(g2[3][1]);
      float og = __builtin_amdgcn_rcpf(1.0f + eo);
      c1 = fg * c1 + ig * gg;
      float ec = __builtin_amdgcn_exp2f(fminf(c1 * (-2.0f*LOG2E), 126.0f));
      float rc = __builtin_amdgcn_rcpf(1.0f + ec);
      h1 = og * ((1.0f - ec) * rc);
    }
    po_p0 = h0 * woj;
    po_p1 = h1 * woj;

    // ---- 8. write h' (bf16) into next-step A-frag rows 0..7 ----
    hfrag[wr][kcp][q2][row0    ][jj] = (__bf16)h0;
    hfrag[wr][kcp][q2][row0 + 1][jj] = (__bf16)h1;

    // ---- 9. convert next x (off the lgkm chain) ----
#pragma unroll
    for (int j = 0; j < 8; ++j) ax[j] = (__bf16)xv[j];

    BAR();  // lgkmcnt-only barrier
  }

  // ---- epilogue: drain the 2-step head pipeline ----
  // finalize data NT-2 (written at t=NT-1 into buf (NT-2)&1 = NT&1)
  if (w == 7 && lane < 8) {
    float4_t p0 = *(const float4_t*)&opart[NT & 1][lane][0];
    float4_t p1 = *(const float4_t*)&opart[NT & 1][lane][4];
    float v = p0[0]+p0[1]+p0[2]+p0[3]+p1[0]+p1[1]+p1[2]+p1[3] + bo;
    out[((size_t)(bq*8 + lane)*NT + (NT - 2))*NP + net] = v;
  }
  // reduce + publish data NT-1
  {
    float a0 = po_p0, a1 = po_p1;
#pragma unroll
    for (int m = 1; m < 16; m <<= 1) {
      a0 += __shfl_xor(a0, m, 64);
      a1 += __shfl_xor(a1, m, 64);
    }
    if (l16 == 0) {
      opart[(NT - 1) & 1][row0    ][w] = a0;
      opart[(NT - 1) & 1][row0 + 1][w] = a1;
    }
  }
  BAR();
  if (w == 7 && lane < 8) {
    float4_t p0 = *(const float4_t*)&opart[(NT - 1) & 1][lane][0];
    float4_t p1 = *(const float4_t*)&opart[(NT - 1) & 1][lane][4];
    float v = p0[0]+p0[1]+p0[2]+p0[3]+p1[0]+p1[1]+p1[2]+p1[3] + bo;
    out[((size_t)(bq*8 + lane)*NT + (NT - 1))*NP + net] = v;
  }
}

extern "C" void kernel_launch(void* const* d_in, const int* in_sizes, int n_in,
                              void* d_out, int out_size, void* d_ws, size_t ws_size,
                              hipStream_t stream) {
  const float* X    = (const float*)d_in[0];
  const float* Wih  = (const float*)d_in[1];
  const float* Whh  = (const float*)d_in[2];
  const float* bih  = (const float*)d_in[3];
  const float* bhh  = (const float*)d_in[4];
  const float* Wout = (const float*)d_in[5];
  const float* bout = (const float*)d_in[6];
  float* out = (float*)d_out;
  (void)in_sizes; (void)n_in; (void)out_size; (void)d_ws; (void)ws_size;

  clstm_fused<<<128, 512, 0, stream>>>(X, Wih, Whh, bih, bhh, Wout, bout, out);
}

// Round 6
// 328.914 us; speedup vs baseline: 1.1978x; 1.0220x over previous
//
#include <hip/hip_runtime.h>
#include <stdint.h>

// Problem constants (match reference)
#define NP 32    // num networks (P)
#define NH 128   // hidden (H)
#define NB 32    // batch (B)
#define NT 256   // time (T)
#define FH 512   // 4*H

typedef __attribute__((ext_vector_type(4))) float float4_t;
typedef __attribute__((ext_vector_type(8))) __bf16 bf16x8;

static __device__ __forceinline__ float4_t mfma_bf16(bf16x8 a, bf16x8 b, float4_t c) {
  return __builtin_amdgcn_mfma_f32_16x16x32_bf16(a, b, c, 0, 0, 0);
}

#define LOG2E 1.4426950408889634f

// Raw workgroup barrier: drains LDS ops only (cross-wave h visibility), does
// NOT drain vmcnt — pending global loads/stores stay in flight across it.
#define BAR() __asm__ volatile("s_waitcnt lgkmcnt(0)\n\ts_barrier" ::: "memory")

// R6 = R2's proven recurrence (242us main, ~90% local busy) + MFMA-fused head.
// SESSION RULES (counter-derived):
//  - R5 post-mortem: __shfl_* are DS-pipe ops (~740 cyc/CU/step for 16/lane)
//    and are lgkm-drained at the barrier -> NOTHING new on the DS pipe or
//    cross-lane inside the step loop.
//  - R4 post-mortem: 1 wave/SIMD exposes the full latency chain; keep 8
//    waves (2/SIMD).
//  - R3 post-mortem: no global loads threaded through the lgkm chain; x via
//    register prefetch only.
// Head fusion: po[b] = sum_k h[b][k]*wout[k] is 4 extra mfma_16x16x32 on the
// ALREADY-LOADED ah frags, with B[k][n] = wout[k] broadcast over n. Only
// wave 0 runs them (wave-uniform branch); lanes l16==0 store 4 dwords
// fire-and-forget. Zero trans, zero DS, zero shuffles; one step late
// (ah = h_{t-1} -> out[t-1]); epilogue finishes t = NT-1.
//
// Grid: 64 blocks = 32 nets x 2 batch-halves (16 batches, full M=16 tile).
// Block: 512 thr = 8 waves; wave w owns units [16w,16w+16) = 4 gate N-tiles.
// Weights in VGPRs (bf16 B-frags); gate scales folded: i,f,o cols x -log2e
// (sigmoid = rcp(1+exp2(y))), g cols x -2log2e (tanh = (1-e)*rcp(1+e)).
__global__ __launch_bounds__(512, 1) void clstm_fused(
    const float* __restrict__ X, const float* __restrict__ Wih,
    const float* __restrict__ Whh, const float* __restrict__ bih,
    const float* __restrict__ bhh, const float* __restrict__ Wout,
    const float* __restrict__ bout, float* __restrict__ out)
{
  const int net = blockIdx.x >> 1, bg = blockIdx.x & 1;
  const int tid = threadIdx.x;
  const int w = tid >> 6, lane = tid & 63;
  const int quad = lane >> 4, l16 = lane & 15;

  // h A-fragments, double buffered: [buf][kchunk][kquad][m][j] (16B rows)
  __shared__ __bf16 hfrag[2][4][4][16][8];

  { // zero the t=0 h buffer (h0 = 0): 4KB = 1024 ints, 2 per thread
    int* hz = (int*)&hfrag[0][0][0][0][0];
    hz[2*tid] = 0; hz[2*tid+1] = 0;
  }
  __syncthreads();  // once, outside the loop — full drain fine here

  // ---- load weights into register B-fragments (one-time) ----
  // B-frag layout for 16x16x32: lane holds B[k = quad*8 + j][n = l16].
  bf16x8 bfrag[4][5];
  float4_t bias4[4];
#pragma unroll
  for (int g = 0; g < 4; ++g) {
    const float scale = (g == 2) ? (-2.0f*LOG2E) : (-LOG2E);
    const int col = g*NH + w*16 + l16;
#pragma unroll
    for (int kc = 0; kc < 5; ++kc) {
      const float* src = (kc == 0) ? (Wih + ((size_t)net*FH + col)*NP + quad*8)
                                   : (Whh + ((size_t)net*FH + col)*NH + (kc-1)*32 + quad*8);
      bf16x8 bf;
#pragma unroll
      for (int j = 0; j < 8; ++j) bf[j] = (__bf16)(src[j] * scale);
      bfrag[g][kc] = bf;
    }
    const float b = (bih[net*FH + col] + bhh[net*FH + col]) * scale;
    bias4[g] = (float4_t){b, b, b, b};
  }

  // head B-frags: B[k][n] = wout[k] broadcast over all 16 cols n.
  bf16x8 wof[4];
#pragma unroll
  for (int kc = 0; kc < 4; ++kc) {
    const float* wp = Wout + net*NH + kc*32 + quad*8;
#pragma unroll
    for (int j = 0; j < 8; ++j) wof[kc][j] = (__bf16)wp[j];
  }
  const float bo = bout[net];

  float4_t c4 = {0.f, 0.f, 0.f, 0.f};  // c state: lane's unit, batches quad*4+r

  // x A-frag source: lane reads X[bg*16+l16][t][quad*8 .. +8]
  const float* xrow = X + (size_t)(bg*16 + l16)*(NT*NP) + quad*8;

  // h write coords for unit hj = w*16 + l16
  const int kcp = w >> 1, q2 = ((w & 1) << 1) | (l16 >> 3), jj = l16 & 7;

  // head store base: out[(bg*16 + quad*4 + r)*NT*NP + t*NP + net]
  float* outp = out + ((size_t)(bg*16 + quad*4))*(NT*NP) + net;

  // preload + convert x for t=0
  bf16x8 ax;
  {
    float xv0[8];
    *(float4_t*)&xv0[0] = *(const float4_t*)xrow;
    *(float4_t*)&xv0[4] = *(const float4_t*)(xrow + 4);
#pragma unroll
    for (int j = 0; j < 8; ++j) ax[j] = (__bf16)xv0[j];
  }

  for (int t = 0; t < NT; ++t) {
    const int rd = t & 1, wr = rd ^ 1;

    // ---- 1. h A-frags first (LDS latency overlapped by 2-3 below) ----
    bf16x8 ah[4];
#pragma unroll
    for (int kc = 0; kc < 4; ++kc)
      ah[kc] = *(const bf16x8*)&hfrag[rd][kc][quad][l16][0];

    // ---- 2. prefetch x for t+1 (fire-and-forget; converted at step end) ----
    float xv[8];
    {
      const int tn = (t + 1 < NT) ? t + 1 : t;
      const float* xp = xrow + tn*NP;
      *(float4_t*)&xv[0] = *(const float4_t*)xp;
      *(float4_t*)&xv[4] = *(const float4_t*)(xp + 4);
    }

    // ---- 3. gate MFMAs: 4 gates, two parallel chains each (depth 3+2) ----
    float4_t acc[4];
#pragma unroll
    for (int g = 0; g < 4; ++g) {
      float4_t a0 = bias4[g];
      float4_t a1 = {0.f, 0.f, 0.f, 0.f};
      a0 = mfma_bf16(ax,    bfrag[g][0], a0);
      a1 = mfma_bf16(ah[2], bfrag[g][3], a1);
      a0 = mfma_bf16(ah[0], bfrag[g][1], a0);
      a1 = mfma_bf16(ah[3], bfrag[g][4], a1);
      a0 = mfma_bf16(ah[1], bfrag[g][2], a0);
      acc[g] = a0 + a1;
    }

    // ---- 4. fused head (wave 0 only; uses ah = h_{t-1} -> out[t-1]) ----
    // 4 extra MFMAs on the matrix pipe, result only feeds a f&f store.
    if (w == 0 && t > 0) {
      float4_t po = {bo, bo, bo, bo};
#pragma unroll
      for (int kc = 0; kc < 4; ++kc) po = mfma_bf16(ah[kc], wof[kc], po);
      if (l16 == 0) {
#pragma unroll
        for (int r = 0; r < 4; ++r)
          outp[(size_t)r*(NT*NP) + (t - 1)*NP] = po[r];
      }
    }

    // ---- 5. activations + state update (fp32), 4 pairs per lane ----
    float4_t h4;
#pragma unroll
    for (int r = 0; r < 4; ++r) {
      float ei = __builtin_amdgcn_exp2f(acc[0][r]);
      float ig = __builtin_amdgcn_rcpf(1.0f + ei);            // sigmoid(i)
      float ef = __builtin_amdgcn_exp2f(acc[1][r]);
      float fg = __builtin_amdgcn_rcpf(1.0f + ef);            // sigmoid(f)
      float eg = __builtin_amdgcn_exp2f(fminf(acc[2][r], 126.0f));
      float rg = __builtin_amdgcn_rcpf(1.0f + eg);
      float gg = (1.0f - eg) * rg;                            // tanh(g)
      float eo = __builtin_amdgcn_exp2f(acc[3][r]);
      float og = __builtin_amdgcn_rcpf(1.0f + eo);            // sigmoid(o)
      float c  = fg * c4[r] + ig * gg;
      c4[r] = c;
      float ec = __builtin_amdgcn_exp2f(fminf(c * (-2.0f*LOG2E), 126.0f));
      float rc = __builtin_amdgcn_rcpf(1.0f + ec);
      float th = (1.0f - ec) * rc;                            // tanh(c)
      h4[r] = og * th;
    }

    // ---- 6. write h' (bf16) into next-step A-frag buffer ----
#pragma unroll
    for (int r = 0; r < 4; ++r)
      hfrag[wr][kcp][q2][quad*4 + r][jj] = (__bf16)h4[r];

    // ---- 7. convert next x (off the lgkm chain) ----
#pragma unroll
    for (int j = 0; j < 8; ++j) ax[j] = (__bf16)xv[j];

    BAR();  // lgkmcnt-only barrier
  }

  // ---- epilogue: head for t = NT-1 (h_{NT-1} is in hfrag[NT&1]) ----
  if (w == 0) {
    bf16x8 ahf[4];
#pragma unroll
    for (int kc = 0; kc < 4; ++kc)
      ahf[kc] = *(const bf16x8*)&hfrag[NT & 1][kc][quad][l16][0];
    float4_t po = {bo, bo, bo, bo};
#pragma unroll
    for (int kc = 0; kc < 4; ++kc) po = mfma_bf16(ahf[kc], wof[kc], po);
    if (l16 == 0) {
#pragma unroll
      for (int r = 0; r < 4; ++r)
        outp[(size_t)r*(NT*NP) + (NT - 1)*NP] = po[r];
    }
  }
}

extern "C" void kernel_launch(void* const* d_in, const int* in_sizes, int n_in,
                              void* d_out, int out_size, void* d_ws, size_t ws_size,
                              hipStream_t stream) {
  const float* X    = (const float*)d_in[0];
  const float* Wih  = (const float*)d_in[1];
  const float* Whh  = (const float*)d_in[2];
  const float* bih  = (const float*)d_in[3];
  const float* bhh  = (const float*)d_in[4];
  const float* Wout = (const float*)d_in[5];
  const float* bout = (const float*)d_in[6];
  float* out = (float*)d_out;
  (void)in_sizes; (void)n_in; (void)out_size; (void)d_ws; (void)ws_size;

  clstm_fused<<<64, 512, 0, stream>>>(X, Wih, Whh, bih, bhh, Wout, bout, out);
}

// Round 7
// 287.176 us; speedup vs baseline: 1.3719x; 1.1453x over previous
//
#include <hip/hip_runtime.h>
#include <stdint.h>

// Problem constants (match reference)
#define NP 32    // num networks (P)
#define NH 128   // hidden (H)
#define NB 32    // batch (B)
#define NT 256   // time (T)
#define FH 512   // 4*H

typedef __attribute__((ext_vector_type(4))) float float4_t;
typedef __attribute__((ext_vector_type(8))) __bf16 bf16x8;

static __device__ __forceinline__ float4_t mfma_bf16(bf16x8 a, bf16x8 b, float4_t c) {
  return __builtin_amdgcn_mfma_f32_16x16x32_bf16(a, b, c, 0, 0, 0);
}

#define LOG2E 1.4426950408889634f

// Raw workgroup barrier: drains LDS ops only (cross-wave h visibility), does
// NOT drain vmcnt — pending global loads/stores stay in flight across it.
#define BAR() __asm__ volatile("s_waitcnt lgkmcnt(0)\n\ts_barrier" ::: "memory")

// R7: duplicate-row redistribution — R5's lane-balance with ZERO DS-pipe cost.
// SESSION RULES (counter-derived):
//  - R5: __shfl_* are DS-pipe ops and lgkm-drain at the barrier -> no new
//    DS/cross-lane ops in the step loop. Redistribution here uses v_cndmask.
//  - R4: 1 wave/SIMD exposes the full latency chain; keep 8 waves (2/SIMD).
//  - R3: no global loads threaded through the lgkm chain; x register prefetch.
//  - R6: dependent MFMA chains straggle wave 0 block-wide; head split 2+2.
//
// Grid: 128 blocks = 32 nets x 4 batch-quarters (M=8 real batches).
// Trick: A rows 8..15 DUPLICATE rows 0..7 (LDS stores only 8 rows; lanes
// l16 and l16+8 read the same address -> broadcast, conflict-free). C rows
// 8..15 then duplicate 0..7, so every lane holds valid (batch,unit) pairs:
//   lane picks regs {0,1} if quad<2 else {2,3} (one v_cndmask per gate-reg),
//   covering rows {0,1}q0 {4,5}q1 {2,3}q2 {6,7}q3 exactly once.
// Per-wave per-step: 20 trans (was 40), 2 ds_write_b16 (was 4); per-CU MFMA
// and DS-read unchanged; active CUs double to 128.
__global__ __launch_bounds__(512, 1) void clstm_fused(
    const float* __restrict__ X, const float* __restrict__ Wih,
    const float* __restrict__ Whh, const float* __restrict__ bih,
    const float* __restrict__ bhh, const float* __restrict__ Wout,
    const float* __restrict__ bout, float* __restrict__ out)
{
  const int net = blockIdx.x >> 2, bq = blockIdx.x & 3;
  const int tid = threadIdx.x;
  const int w = tid >> 6, lane = tid & 63;
  const int quad = lane >> 4, l16 = lane & 15;

  // h A-fragments, double buffered, 8 DISTINCT rows: [buf][kc][kquad][m<8][j]
  __shared__ __bf16 hfrag[2][4][4][8][8];   // 4 KB total

  { // zero BOTH buffers (h0 = 0): 4KB = 1024 ints, 2 per thread
    int* hz = (int*)hfrag;
    hz[2*tid] = 0; hz[2*tid+1] = 0;
  }
  __syncthreads();  // once, outside the loop

  // ---- load weights into register B-fragments (one-time) ----
  // B-frag layout for 16x16x32: lane holds B[k = quad*8 + j][n = l16].
  bf16x8 bfrag[4][5];
  float4_t bias4[4];
#pragma unroll
  for (int g = 0; g < 4; ++g) {
    const float scale = (g == 2) ? (-2.0f*LOG2E) : (-LOG2E);
    const int col = g*NH + w*16 + l16;
#pragma unroll
    for (int kc = 0; kc < 5; ++kc) {
      const float* src = (kc == 0) ? (Wih + ((size_t)net*FH + col)*NP + quad*8)
                                   : (Whh + ((size_t)net*FH + col)*NH + (kc-1)*32 + quad*8);
      bf16x8 bf;
#pragma unroll
      for (int j = 0; j < 8; ++j) bf[j] = (__bf16)(src[j] * scale);
      bfrag[g][kc] = bf;
    }
    const float b = (bih[net*FH + col] + bhh[net*FH + col]) * scale;
    bias4[g] = (float4_t){b, b, b, b};
  }

  // head B-frags: B[k][n] = wout[k] broadcast over all 16 cols n.
  bf16x8 wof[4];
#pragma unroll
  for (int kc = 0; kc < 4; ++kc) {
    const float* wp = Wout + net*NH + kc*32 + quad*8;
#pragma unroll
    for (int j = 0; j < 8; ++j) wof[kc][j] = (__bf16)wp[j];
  }
  const float bo = bout[net];

  float c0 = 0.f, c1 = 0.f;   // c state for this lane's 2 (batch,unit) pairs

  // x A-frag source: logical row l16 -> batch bq*8 + (l16&7) (rows 8-15 dup)
  const float* xrow = X + (size_t)(bq*8 + (l16 & 7))*(NT*NP) + quad*8;

  // h write coords for unit u = w*16 + l16
  const int kcp = w >> 1, q2 = ((w & 1) << 1) | (l16 >> 3), jj = l16 & 7;
  // this lane's two local batch rows after dup-redistribution
  const int row0 = ((quad & 1) << 2) | ((quad >> 1) << 1);
  const bool qlo = quad < 2;

  // head store base: out[(bq*8 + quad*4 + r)*NT*NP + t*NP + net] (quad<2 only)
  float* outp = out + ((size_t)(bq*8 + quad*4))*(NT*NP) + net;

  // preload + convert x for t=0
  bf16x8 ax;
  {
    float xv0[8];
    *(float4_t*)&xv0[0] = *(const float4_t*)xrow;
    *(float4_t*)&xv0[4] = *(const float4_t*)(xrow + 4);
#pragma unroll
    for (int j = 0; j < 8; ++j) ax[j] = (__bf16)xv0[j];
  }

  for (int t = 0; t < NT; ++t) {
    const int rd = t & 1, wr = rd ^ 1;

    // ---- 1. h A-frags first; lanes l16 and l16+8 broadcast-read row l16&7 --
    bf16x8 ah[4];
#pragma unroll
    for (int kc = 0; kc < 4; ++kc)
      ah[kc] = *(const bf16x8*)&hfrag[rd][kc][quad][l16 & 7][0];

    // ---- 2. prefetch x for t+1 (fire-and-forget; converted at step end) ----
    float xv[8];
    {
      const int tn = (t + 1 < NT) ? t + 1 : t;
      const float* xp = xrow + tn*NP;
      *(float4_t*)&xv[0] = *(const float4_t*)xp;
      *(float4_t*)&xv[4] = *(const float4_t*)(xp + 4);
    }

    // ---- 3. gate MFMAs: 4 gates, two parallel chains each (depth 3+2) ----
    float4_t acc[4];
#pragma unroll
    for (int g = 0; g < 4; ++g) {
      float4_t a0 = bias4[g];
      float4_t a1 = {0.f, 0.f, 0.f, 0.f};
      a0 = mfma_bf16(ax,    bfrag[g][0], a0);
      a1 = mfma_bf16(ah[2], bfrag[g][3], a1);
      a0 = mfma_bf16(ah[0], bfrag[g][1], a0);
      a1 = mfma_bf16(ah[3], bfrag[g][4], a1);
      a0 = mfma_bf16(ah[1], bfrag[g][2], a0);
      acc[g] = a0 + a1;
    }

    // ---- 4. fused head (wave 0 only; ah = h_{t-1} -> out[t-1]).
    // Two 2-deep chains (R6 post-mortem: 4-deep chain straggled the block).
    if (w == 0 && t > 0) {
      float4_t p0 = {bo, bo, bo, bo};
      float4_t p1 = {0.f, 0.f, 0.f, 0.f};
      p0 = mfma_bf16(ah[0], wof[0], p0);
      p1 = mfma_bf16(ah[2], wof[2], p1);
      p0 = mfma_bf16(ah[1], wof[1], p0);
      p1 = mfma_bf16(ah[3], wof[3], p1);
      float4_t po = p0 + p1;
      if (l16 == 0 && qlo) {     // rows 0-7 live in quads 0,1
#pragma unroll
        for (int r = 0; r < 4; ++r)
          outp[(size_t)r*(NT*NP) + (t - 1)*NP] = po[r];
      }
    }

    // ---- 5. select this lane's 2 valid pairs (v_cndmask, NOT shuffles) ----
    float g2[4][2];
#pragma unroll
    for (int g = 0; g < 4; ++g) {
      g2[g][0] = qlo ? acc[g][0] : acc[g][2];
      g2[g][1] = qlo ? acc[g][1] : acc[g][3];
    }

    // ---- 6. activations + state update: exactly 2 pairs per lane ----
    float h0, h1;
    {
      float ei = __builtin_amdgcn_exp2f(g2[0][0]);
      float ig = __builtin_amdgcn_rcpf(1.0f + ei);
      float ef = __builtin_amdgcn_exp2f(g2[1][0]);
      float fg = __builtin_amdgcn_rcpf(1.0f + ef);
      float eg = __builtin_amdgcn_exp2f(fminf(g2[2][0], 126.0f));
      float rg = __builtin_amdgcn_rcpf(1.0f + eg);
      float gg = (1.0f - eg) * rg;
      float eo = __builtin_amdgcn_exp2f(g2[3][0]);
      float og = __builtin_amdgcn_rcpf(1.0f + eo);
      c0 = fg * c0 + ig * gg;
      float ec = __builtin_amdgcn_exp2f(fminf(c0 * (-2.0f*LOG2E), 126.0f));
      float rc = __builtin_amdgcn_rcpf(1.0f + ec);
      h0 = og * ((1.0f - ec) * rc);
    }
    {
      float ei = __builtin_amdgcn_exp2f(g2[0][1]);
      float ig = __builtin_amdgcn_rcpf(1.0f + ei);
      float ef = __builtin_amdgcn_exp2f(g2[1][1]);
      float fg = __builtin_amdgcn_rcpf(1.0f + ef);
      float eg = __builtin_amdgcn_exp2f(fminf(g2[2][1], 126.0f));
      float rg = __builtin_amdgcn_rcpf(1.0f + eg);
      float gg = (1.0f - eg) * rg;
      float eo = __builtin_amdgcn_exp2f(g2[3][1]);
      float og = __builtin_amdgcn_rcpf(1.0f + eo);
      c1 = fg * c1 + ig * gg;
      float ec = __builtin_amdgcn_exp2f(fminf(c1 * (-2.0f*LOG2E), 126.0f));
      float rc = __builtin_amdgcn_rcpf(1.0f + ec);
      h1 = og * ((1.0f - ec) * rc);
    }

    // ---- 7. write h' (bf16): 2 ds_write_b16 into distinct rows <8 ----
    hfrag[wr][kcp][q2][row0    ][jj] = (__bf16)h0;
    hfrag[wr][kcp][q2][row0 + 1][jj] = (__bf16)h1;

    // ---- 8. convert next x (off the lgkm chain) ----
#pragma unroll
    for (int j = 0; j < 8; ++j) ax[j] = (__bf16)xv[j];

    BAR();  // lgkmcnt-only barrier
  }

  // ---- epilogue: head for t = NT-1 (h_{NT-1} is in hfrag[NT&1]) ----
  if (w == 0) {
    bf16x8 ahf[4];
#pragma unroll
    for (int kc = 0; kc < 4; ++kc)
      ahf[kc] = *(const bf16x8*)&hfrag[NT & 1][kc][quad][l16 & 7][0];
    float4_t p0 = {bo, bo, bo, bo};
    float4_t p1 = {0.f, 0.f, 0.f, 0.f};
    p0 = mfma_bf16(ahf[0], wof[0], p0);
    p1 = mfma_bf16(ahf[2], wof[2], p1);
    p0 = mfma_bf16(ahf[1], wof[1], p0);
    p1 = mfma_bf16(ahf[3], wof[3], p1);
    float4_t po = p0 + p1;
    if (l16 == 0 && qlo) {
#pragma unroll
      for (int r = 0; r < 4; ++r)
        outp[(size_t)r*(NT*NP) + (NT - 1)*NP] = po[r];
    }
  }
}

extern "C" void kernel_launch(void* const* d_in, const int* in_sizes, int n_in,
                              void* d_out, int out_size, void* d_ws, size_t ws_size,
                              hipStream_t stream) {
  const float* X    = (const float*)d_in[0];
  const float* Wih  = (const float*)d_in[1];
  const float* Whh  = (const float*)d_in[2];
  const float* bih  = (const float*)d_in[3];
  const float* bhh  = (const float*)d_in[4];
  const float* Wout = (const float*)d_in[5];
  const float* bout = (const float*)d_in[6];
  float* out = (float*)d_out;
  (void)in_sizes; (void)n_in; (void)out_size; (void)d_ws; (void)ws_size;

  clstm_fused<<<128, 512, 0, stream>>>(X, Wih, Whh, bih, bhh, Wout, bout, out);
}

// Round 8
// 257.534 us; speedup vs baseline: 1.5298x; 1.1151x over previous
//
#include <hip/hip_runtime.h>
#include <stdint.h>

// Problem constants (match reference)
#define NP 32    // num networks (P)
#define NH 128   // hidden (H)
#define NB 32    // batch (B)
#define NT 256   // time (T)
#define FH 512   // 4*H

typedef __attribute__((ext_vector_type(4))) float float4_t;
typedef __attribute__((ext_vector_type(8))) __bf16 bf16x8;

static __device__ __forceinline__ float4_t mfma_bf16(bf16x8 a, bf16x8 b, float4_t c) {
  return __builtin_amdgcn_mfma_f32_16x16x32_bf16(a, b, c, 0, 0, 0);
}

#define LOG2E 1.4426950408889634f

// Raw workgroup barrier: drains LDS ops only (cross-wave h visibility), does
// NOT drain vmcnt — pending global loads/stores stay in flight across it.
#define BAR() __asm__ volatile("s_waitcnt lgkmcnt(0)\n\ts_barrier" ::: "memory")

// R8: M=4 / 256 blocks — final free trans/VALU halving (all 256 CUs).
// Step-time model (validated R2/R4/R5/R6/R7 to within ~5%):
//   step ~ MFMA_pipe(795 cyc, invariant: 164 instr/block x 4.85) +
//          trans_issue(instr/SIMD x 8) + VALU_issue + exposure(~700).
// SESSION RULES: no DS-pipe/cross-lane ops in the loop (R5); 8 waves =
// 2/SIMD (R4); x via register prefetch only (R3); no deep dependent MFMA
// chains on one wave (R6).
//
// Grid: 256 blocks = 32 nets x 8 batch-groups (M=4 real batches).
// Dup trick: A rows hold batch l16&3 (4x dup) -> C reg r of quad q is batch
// r; lane adopts reg index = quad (v_cndmask select, covers 4 batches x 16
// units exactly). Trans = 10/wave/step.
// Micro: x-MFMAs issued before h-MFMAs (fills LDS latency); c-state kept
// pre-scaled by -2log2e (1 mul off the h critical chain); x prefetch
// pointer-incremented + scalar-guarded; head (wave 0, two 2-deep MFMA
// chains) issued after the h-write.
__global__ __launch_bounds__(512, 1) void clstm_fused(
    const float* __restrict__ X, const float* __restrict__ Wih,
    const float* __restrict__ Whh, const float* __restrict__ bih,
    const float* __restrict__ bhh, const float* __restrict__ Wout,
    const float* __restrict__ bout, float* __restrict__ out)
{
  const int net = blockIdx.x >> 3, bq = blockIdx.x & 7;
  const int tid = threadIdx.x;
  const int w = tid >> 6, lane = tid & 63;
  const int quad = lane >> 4, l16 = lane & 15;

  // h A-fragments, double buffered, 4 DISTINCT rows: [buf][kc][kquad][m<4][j]
  __shared__ __bf16 hfrag[2][4][4][4][8];   // 2 KB total

  { // zero BOTH buffers (h0 = 0): 2KB = 512 ints, 1 per thread
    ((int*)hfrag)[tid] = 0;
  }
  __syncthreads();  // once, outside the loop

  // ---- load weights into register B-fragments (one-time) ----
  // B-frag layout for 16x16x32: lane holds B[k = quad*8 + j][n = l16].
  bf16x8 bfrag[4][5];
  float4_t bias4[4];
#pragma unroll
  for (int g = 0; g < 4; ++g) {
    const float scale = (g == 2) ? (-2.0f*LOG2E) : (-LOG2E);
    const int col = g*NH + w*16 + l16;
#pragma unroll
    for (int kc = 0; kc < 5; ++kc) {
      const float* src = (kc == 0) ? (Wih + ((size_t)net*FH + col)*NP + quad*8)
                                   : (Whh + ((size_t)net*FH + col)*NH + (kc-1)*32 + quad*8);
      bf16x8 bf;
#pragma unroll
      for (int j = 0; j < 8; ++j) bf[j] = (__bf16)(src[j] * scale);
      bfrag[g][kc] = bf;
    }
    const float b = (bih[net*FH + col] + bhh[net*FH + col]) * scale;
    bias4[g] = (float4_t){b, b, b, b};
  }

  // head B-frags: B[k][n] = wout[k] broadcast over all 16 cols n.
  bf16x8 wof[4];
#pragma unroll
  for (int kc = 0; kc < 4; ++kc) {
    const float* wp = Wout + net*NH + kc*32 + quad*8;
#pragma unroll
    for (int j = 0; j < 8; ++j) wof[kc][j] = (__bf16)wp[j];
  }
  const float bo = bout[net];

  // c state, PRE-SCALED by -2log2e (saves a mul on the h critical chain)
  float cs = 0.f;
  const float S2 = -2.0f*LOG2E;

  // x A-frag source: row l16 -> batch bq*4 + (l16&3) (4x dup)
  const float* xrow = X + (size_t)(bq*4 + (l16 & 3))*(NT*NP) + quad*8;

  // h write coords for unit u = w*16 + l16; row = quad (this lane's batch)
  const int kcp = w >> 1, q2 = ((w & 1) << 1) | (l16 >> 3), jj = l16 & 7;

  // head store base: out[(bq*4 + r)*NT*NP + t*NP + net], stored by
  // wave 0, quad 0, l16 0 (C rows r = batches r, dup across quads).
  float* outp = out + ((size_t)bq*4)*(NT*NP) + net;

  // preload + convert x for t=0; xp then walks t=1..NT-1
  bf16x8 ax;
  {
    float xv0[8];
    *(float4_t*)&xv0[0] = *(const float4_t*)xrow;
    *(float4_t*)&xv0[4] = *(const float4_t*)(xrow + 4);
#pragma unroll
    for (int j = 0; j < 8; ++j) ax[j] = (__bf16)xv0[j];
  }
  const float* xp = xrow + NP;
  float xv[8] = {0.f,0.f,0.f,0.f,0.f,0.f,0.f,0.f};

  for (int t = 0; t < NT; ++t) {
    const int rd = t & 1, wr = rd ^ 1;

    // ---- 1. h A-frags (row = l16&3; 4-lane same-address broadcast) ----
    bf16x8 ah[4];
#pragma unroll
    for (int kc = 0; kc < 4; ++kc)
      ah[kc] = *(const bf16x8*)&hfrag[rd][kc][quad][l16 & 3][0];

    // ---- 2. x-MFMAs first: no LDS dependence, fills ds_read latency ----
    float4_t accx[4];
#pragma unroll
    for (int g = 0; g < 4; ++g)
      accx[g] = mfma_bf16(ax, bfrag[g][0], bias4[g]);

    // ---- 3. x prefetch for t+1 (scalar-guarded, pointer-incremented) ----
    if (t + 1 < NT) {
      *(float4_t*)&xv[0] = *(const float4_t*)xp;
      *(float4_t*)&xv[4] = *(const float4_t*)(xp + 4);
    }

    // ---- 4. h-MFMAs: 4 gates, two parallel chains each (depth 2) ----
    float4_t acc[4];
#pragma unroll
    for (int g = 0; g < 4; ++g) {
      float4_t a0 = mfma_bf16(ah[0], bfrag[g][1], accx[g]);
      float4_t a1 = mfma_bf16(ah[2], bfrag[g][3], (float4_t){0.f,0.f,0.f,0.f});
      a0 = mfma_bf16(ah[1], bfrag[g][2], a0);
      a1 = mfma_bf16(ah[3], bfrag[g][4], a1);
      acc[g] = a0 + a1;
    }

    // ---- 5. select this lane's batch (= quad) via cndmask, NOT shuffles --
    float gv[4];
#pragma unroll
    for (int g = 0; g < 4; ++g) {
      float a01 = (quad & 1) ? acc[g][1] : acc[g][0];
      float a23 = (quad & 1) ? acc[g][3] : acc[g][2];
      gv[g] = (quad & 2) ? a23 : a01;
    }

    // ---- 6. activation + state update: ONE (batch,unit) pair per lane ----
    float h;
    {
      float ei = __builtin_amdgcn_exp2f(gv[0]);
      float ig = __builtin_amdgcn_rcpf(1.0f + ei);            // sigmoid(i)
      float ef = __builtin_amdgcn_exp2f(gv[1]);
      float fg = __builtin_amdgcn_rcpf(1.0f + ef);            // sigmoid(f)
      float eg = __builtin_amdgcn_exp2f(fminf(gv[2], 126.0f));
      float rg = __builtin_amdgcn_rcpf(1.0f + eg);
      float t0 = S2 * rg;
      float gg2 = t0 - t0 * eg;                               // tanh(g)*S2
      float eo = __builtin_amdgcn_exp2f(gv[3]);
      float og = __builtin_amdgcn_rcpf(1.0f + eo);            // sigmoid(o)
      cs = fg * cs + ig * gg2;                                // c * S2
      float ec = __builtin_amdgcn_exp2f(fminf(cs, 126.0f));
      float rc = __builtin_amdgcn_rcpf(1.0f + ec);
      float th = rc - ec * rc;                                // tanh(c)
      h = og * th;
    }

    // ---- 7. write h' (bf16): 1 ds_write_b16, row = quad ----
    hfrag[wr][kcp][q2][quad][jj] = (__bf16)h;

    // ---- 8. fused head (wave 0; ah = h_{t-1} -> out[t-1]) ----
    if (w == 0 && t > 0) {
      float4_t p0 = {bo, bo, bo, bo};
      float4_t p1 = {0.f, 0.f, 0.f, 0.f};
      p0 = mfma_bf16(ah[0], wof[0], p0);
      p1 = mfma_bf16(ah[2], wof[2], p1);
      p0 = mfma_bf16(ah[1], wof[1], p0);
      p1 = mfma_bf16(ah[3], wof[3], p1);
      float4_t po = p0 + p1;
      if (lane == 0) {   // quad 0: C rows 0..3 = batches 0..3
#pragma unroll
        for (int r = 0; r < 4; ++r)
          outp[(size_t)r*(NT*NP) + (t - 1)*NP] = po[r];
      }
    }

    // ---- 9. convert next x; advance pointer ----
#pragma unroll
    for (int j = 0; j < 8; ++j) ax[j] = (__bf16)xv[j];
    xp += NP;

    BAR();  // lgkmcnt-only barrier
  }

  // ---- epilogue: head for t = NT-1 (h_{NT-1} is in hfrag[NT&1]) ----
  if (w == 0) {
    bf16x8 ahf[4];
#pragma unroll
    for (int kc = 0; kc < 4; ++kc)
      ahf[kc] = *(const bf16x8*)&hfrag[NT & 1][kc][quad][l16 & 3][0];
    float4_t p0 = {bo, bo, bo, bo};
    float4_t p1 = {0.f, 0.f, 0.f, 0.f};
    p0 = mfma_bf16(ahf[0], wof[0], p0);
    p1 = mfma_bf16(ahf[2], wof[2], p1);
    p0 = mfma_bf16(ahf[1], wof[1], p0);
    p1 = mfma_bf16(ahf[3], wof[3], p1);
    float4_t po = p0 + p1;
    if (lane == 0) {
#pragma unroll
      for (int r = 0; r < 4; ++r)
        outp[(size_t)r*(NT*NP) + (NT - 1)*NP] = po[r];
    }
  }
}

extern "C" void kernel_launch(void* const* d_in, const int* in_sizes, int n_in,
                              void* d_out, int out_size, void* d_ws, size_t ws_size,
                              hipStream_t stream) {
  const float* X    = (const float*)d_in[0];
  const float* Wih  = (const float*)d_in[1];
  const float* Whh  = (const float*)d_in[2];
  const float* bih  = (const float*)d_in[3];
  const float* bhh  = (const float*)d_in[4];
  const float* Wout = (const float*)d_in[5];
  const float* bout = (const float*)d_in[6];
  float* out = (float*)d_out;
  (void)in_sizes; (void)n_in; (void)out_size; (void)d_ws; (void)ws_size;

  clstm_fused<<<256, 512, 0, stream>>>(X, Wih, Whh, bih, bhh, Wout, bout, out);
}